// Round 2
// baseline (119.497 us; speedup 1.0000x reference)
//
#include <hip/hip_runtime.h>

typedef unsigned short u16;
typedef unsigned int u32;
typedef _Float16 half8 __attribute__((ext_vector_type(8)));   // MFMA A/B frag
typedef __attribute__((ext_vector_type(4))) float floatx4;    // MFMA acc

#define LSTRIDE 72            // u16 per LDS row: 64 + 8 pad; bank-clean
#define BIMG (128 * LSTRIDE)  // u16 per tile image (18432 B)

// global -> LDS DMA. LDS dest is wave-uniform base + lane*size.
__device__ __forceinline__ void gl_lds16(const void* g, void* l) {
  __builtin_amdgcn_global_load_lds(
      (const __attribute__((address_space(1))) void*)g,
      (__attribute__((address_space(3))) void*)l, 16, 0, 0);
}
__device__ __forceinline__ void gl_lds4(const void* g, void* l) {
  __builtin_amdgcn_global_load_lds(
      (const __attribute__((address_space(1))) void*)g,
      (__attribute__((address_space(3))) void*)l, 4, 0, 0);
}

// ---------------------------------------------------------------------------
// Precompute: 64 B-panel images (one per (y,kc)) in the EXACT padded LDS
// layout the main kernel DMAs, fp16-converted once; plus K1*colsum(W).
// Bimg[y*8+kc][(pp*64+o)*72 + kk] = fp16(Wpad[kc*64+kk - 2y - pp][o]).
// ---------------------------------------------------------------------------
__global__ __launch_bounds__(256) void byteformer_precompute(
    const float* __restrict__ Wm, u16* __restrict__ Bws,
    float* __restrict__ csumWs) {
  const int t = threadIdx.x;
  const int y = blockIdx.x >> 3, kc = blockIdx.x & 7;
  const int wave = t >> 6, o = t & 63;
  const int pp = wave >> 1, hf = wave & 1;
  u16* img = Bws + (size_t)blockIdx.x * BIMG;
  #pragma unroll
  for (int i = 0; i < 18; ++i) {
    const int kk = (hf * 18 + i) * 2;  // u16 index in row, even, 0..70
    u32 val = 0u;
    if (kk < 64) {
      const int c0 = kc * 64 + kk - 2 * y - pp;
      const int c1 = c0 + 1;
      float f0 = (c0 >= 0 && c0 < 496) ? Wm[c0 * 64 + o] : 0.0f;
      float f1 = (c1 >= 0 && c1 < 496) ? Wm[c1 * 64 + o] : 0.0f;
      u16 h0 = __builtin_bit_cast(unsigned short, (_Float16)f0);
      u16 h1 = __builtin_bit_cast(unsigned short, (_Float16)f1);
      val = (u32)h0 | ((u32)h1 << 16);
    }
    *(u32*)&img[(pp * 64 + o) * LSTRIDE + kk] = val;
  }
  if (blockIdx.x == 0) {  // csum[o] = K1 * sum_c W[c][o]
    __shared__ float red[256];
    float s = 0.0f;
    for (int c = wave * 124; c < wave * 124 + 124; ++c) s += Wm[c * 64 + o];
    red[t] = s;
    __syncthreads();
    if (t < 64)
      csumWs[t] = (1024.0f * (2.0f / 255.0f) + 1.0f) *
                  (red[t] + red[t + 64] + red[t + 128] + red[t + 192]);
  }
}

// ---------------------------------------------------------------------------
// Fused main. Double-buffered As/Bs, ONE barrier per k-chunk:
//   iter kc: [xload(kc+1), B-DMA(kc+1)->nxt] -> MFMA(cur) -> A-stage(kc+1)->nxt
//            -> barrier (drains DMA, publishes A writes)
// Epilogue staged through LDS for fully-coalesced 1KB/wave stores.
// ---------------------------------------------------------------------------
__global__ __launch_bounds__(256, 2) void byteformer_fused(
    const int* __restrict__ x, const u16* __restrict__ Bws,
    const float* __restrict__ csumWs, float* __restrict__ out) {
  __shared__ __align__(16) u16 arena[4 * BIMG];   // A0 A1 B0 B1 = 73728 B

  const int t = threadIdx.x;
  const int mtile = blockIdx.x;        // 0..127 (16 sub-blocks each)
  const int y = blockIdx.y;            // 0..7: p in {2y, 2y+1}

  const int wave = t >> 6, lane = t & 63;
  const int wm = wave >> 1, wn = wave & 1;
  const int quad = lane >> 4, l16 = lane & 15;

  // A staging: thread -> (sub, k-group, q-half)
  const int sA_sub = t >> 4;           // 0..15
  const int sA_kg  = (t >> 1) & 7;     // 0..7
  const int sA_qh  = t & 1;            // 0..1
  const long xrow = ((long)mtile * 16 + sA_sub) * 512;
  const char* bimg0 = (const char*)(Bws + (size_t)y * 8 * BIMG);

  floatx4 acc[4][4];
  #pragma unroll
  for (int mt = 0; mt < 4; ++mt)
    #pragma unroll
    for (int nt = 0; nt < 4; ++nt)
      acc[mt][nt] = floatx4{0.f, 0.f, 0.f, 0.f};

  float cs[4];
  #pragma unroll
  for (int nt = 0; nt < 4; ++nt) cs[nt] = csumWs[nt * 16 + l16];

  int4 ca, cb; int cc;
  auto xload = [&](int kc) {
    const int base = kc * 64 + sA_kg * 8;
    ca = *(const int4*)&x[xrow + base];
    cb = *(const int4*)&x[xrow + base + 4];
    cc = (base + 8 < 512) ? x[xrow + base + 8] : 0;
  };

  auto bdma = [&](int kc, u16* dstb) {   // 18432 B, pure DMA
    const char* src = bimg0 + (size_t)kc * 18432;
    char* dst = (char*)dstb;
    const int woff = wave * 1024;
    #pragma unroll
    for (int j = 0; j < 4; ++j)
      gl_lds16(src + j * 4096 + woff + lane * 16, dst + j * 4096 + woff);
    const int woff4 = 16384 + wave * 256;
    #pragma unroll
    for (int j = 0; j < 2; ++j)
      gl_lds4(src + woff4 + j * 1024 + lane * 4, dst + woff4 + j * 1024);
  };

  // bytes -> windows -> fp16(1024+v) via 0x6400|v; P-trick packing
  auto astage = [&](u16* dstb) {
    const u32 c0 = (u32)ca.x, c1 = (u32)ca.y, c2 = (u32)ca.z, c3 = (u32)ca.w;
    const u32 c4 = (u32)cb.x, c5 = (u32)cb.y, c6 = (u32)cb.z, c7 = (u32)cb.w;
    const u32 c8 = (u32)cc;
    const u32 P0 = ((c0 << 8) | c1) | (((c1 << 8) | c2) << 16);
    const u32 P1 = ((c2 << 8) | c3) | (((c3 << 8) | c4) << 16);
    const u32 P2 = ((c4 << 8) | c5) | (((c5 << 8) | c6) << 16);
    const u32 P3 = ((c6 << 8) | c7) | (((c7 << 8) | c8) << 16);
    u16* arow = &dstb[(sA_sub * 8 + sA_qh * 4) * LSTRIDE + sA_kg * 8];
    #pragma unroll
    for (int qi = 0; qi < 4; ++qi) {
      const int sh = 8 - (sA_qh * 4 + qi);
      int4 d;
      d.x = (int)(((P0 >> sh) & 0x00FF00FFu) | 0x64006400u);
      d.y = (int)(((P1 >> sh) & 0x00FF00FFu) | 0x64006400u);
      d.z = (int)(((P2 >> sh) & 0x00FF00FFu) | 0x64006400u);
      d.w = (int)(((P3 >> sh) & 0x00FF00FFu) | 0x64006400u);
      *(int4*)(arow + qi * LSTRIDE) = d;   // rows 16B-aligned (144B pitch)
    }
  };

  auto compute = [&](const u16* Ab, const u16* Bb) {
    #pragma unroll
    for (int ks = 0; ks < 2; ++ks) {
      const int koff = ks * 32 + quad * 8;
      half8 af[4], bf[4];
      #pragma unroll
      for (int mt = 0; mt < 4; ++mt)
        af[mt] = *(const half8*)&Ab[(wm * 64 + mt * 16 + l16) * LSTRIDE + koff];
      #pragma unroll
      for (int nt = 0; nt < 4; ++nt)
        bf[nt] = *(const half8*)&Bb[(wn * 64 + nt * 16 + l16) * LSTRIDE + koff];
      #pragma unroll
      for (int mt = 0; mt < 4; ++mt)
        #pragma unroll
        for (int nt = 0; nt < 4; ++nt)
          acc[mt][nt] = __builtin_amdgcn_mfma_f32_16x16x32_f16(
              af[mt], bf[nt], acc[mt][nt], 0, 0, 0);
    }
  };

  // ---- prologue: fill buffer 0
  bdma(0, arena + 2 * BIMG);
  xload(0);
  astage(arena);
  __syncthreads();

  // ---- main loop: one barrier per k-chunk
  #pragma unroll
  for (int kc = 0; kc < 8; ++kc) {
    u16* Acur = arena + (kc & 1) * BIMG;
    u16* Bcur = arena + (2 + (kc & 1)) * BIMG;
    u16* Anxt = arena + ((kc + 1) & 1) * BIMG;
    u16* Bnxt = arena + (2 + ((kc + 1) & 1)) * BIMG;
    if (kc < 7) {
      xload(kc + 1);        // consumed by astage below; latency under MFMA
      bdma(kc + 1, Bnxt);   // drained by this iter's barrier, ~full phase away
    }
    compute(Acur, Bcur);
    if (kc < 7) astage(Anxt);
    __syncthreads();
  }

  // ---- epilogue: stage to LDS (16 chunks x 4KB, pitch 1040 floats), then
  // fully-coalesced stores: per wave-instr 64 lanes x 16B = 1KB contiguous.
  float* ep = (float*)arena;           // 66560 B used <= 73728
  const float S = 2.0f / 255.0f;
  #pragma unroll
  for (int mt = 0; mt < 4; ++mt) {
    #pragma unroll
    for (int i = 0; i < 4; ++i) {
      const int mr = wm * 64 + mt * 16 + quad * 4 + i;   // 0..127
      const int sub_l = mr >> 3, q = mr & 7;
      const int rowbase = sub_l * 1040 + wn * 512 + q * 64 + l16;
      #pragma unroll
      for (int nt = 0; nt < 4; ++nt)
        ep[rowbase + nt * 16] = S * acc[mt][nt][i] - cs[nt];
    }
  }
  __syncthreads();

  const long outbase = (long)mtile * 16 * 8192 + (long)y * 1024;
  #pragma unroll
  for (int k2 = 0; k2 < 16; ++k2) {
    const float4 v =
        *(const float4*)((const char*)ep + k2 * 4160 + wave * 1024 + lane * 16);
    *(float4*)&out[outbase + (long)k2 * 8192 + wave * 256 + lane * 4] = v;
  }
}

extern "C" void kernel_launch(void* const* d_in, const int* in_sizes, int n_in,
                              void* d_out, int out_size, void* d_ws, size_t ws_size,
                              hipStream_t stream) {
  const int* x = (const int*)d_in[0];        // (256, 4096) byte values as int32
  const float* Wm = (const float*)d_in[1];   // (496, 64) fp32
  float* out = (float*)d_out;                // (256, 8, 128, 64) fp32
  u16* Bws = (u16*)d_ws;                                    // 1,179,648 B
  float* csumWs = (float*)((char*)d_ws + (size_t)64 * BIMG * 2);  // +256 B
  byteformer_precompute<<<dim3(64), dim3(256), 0, stream>>>(Wm, Bws, csumWs);
  byteformer_fused<<<dim3(128, 8), dim3(256), 0, stream>>>(x, Bws, csumWs, out);
}

// Round 3
// 108.696 us; speedup vs baseline: 1.0994x; 1.0994x over previous
//
#include <hip/hip_runtime.h>

typedef unsigned short u16;
typedef unsigned int u32;
typedef _Float16 half8 __attribute__((ext_vector_type(8)));   // MFMA A/B frag
typedef __attribute__((ext_vector_type(4))) float floatx4;    // MFMA acc

#define LSTRIDE 72            // u16 per LDS row: 64 + 8 pad; bank-clean
#define BIMG (128 * LSTRIDE)  // u16 per tile image (18432 B)

// ---------------------------------------------------------------------------
// Single-dispatch fused kernel.
//   out[sub][p*8+q][o] = S*acc - K1*csum[o],  S = 2/255, K1 = 1024*S+1
//   acc = sum_m fp16(1024 + w[q][m]) * fp16(Wpad[m - p][o])
// BM=128 (16 subs x 8 q), BN=128 (2 p x 64 o), BK=64. 4 waves 2x2, 64x64.
// Double-buffered As/Bs, ONE barrier per k-chunk:
//   iter kc: [xload(kc+1), Wload(kc+1)] -> MFMA(cur) -> A/B-stage(kc+1)->nxt
//            -> barrier
// Loads are register-prefetched; their latency hides under the MFMA phase.
// Epilogue staged through LDS: fully-coalesced 1KB-per-wave-instr stores.
// ---------------------------------------------------------------------------
__global__ __launch_bounds__(256, 2) void byteformer_fused(
    const int* __restrict__ x, const float* __restrict__ Wm,
    float* __restrict__ out) {
  __shared__ __align__(16) u16 arena[4 * BIMG];   // A0 A1 B0 B1 = 73728 B
  __shared__ float part[256];
  __shared__ float csumsh[64];

  const int t = threadIdx.x;
  const int mtile = blockIdx.x;        // 0..127 (16 sub-blocks each)
  const int y = blockIdx.y;            // 0..7: p in {2y, 2y+1}

  const int wave = t >> 6, lane = t & 63;
  const int wm = wave >> 1, wn = wave & 1;
  const int quad = lane >> 4, l16 = lane & 15;

  // A staging: thread -> (sub, k-group, q-half)
  const int sA_sub = t >> 4;           // 0..15
  const int sA_kg  = (t >> 1) & 7;     // 0..7
  const int sA_qh  = t & 1;            // 0..1
  const long xrow = ((long)mtile * 16 + sA_sub) * 512;

  floatx4 acc[4][4];
  #pragma unroll
  for (int mt = 0; mt < 4; ++mt)
    #pragma unroll
    for (int nt = 0; nt < 4; ++nt)
      acc[mt][nt] = floatx4{0.f, 0.f, 0.f, 0.f};

  float csum_local = 0.0f;

  // ---- register prefetch state
  int4 ca, cb; int cc;                 // x bytes (9 ints)
  float f[17];                         // W rows for B-stage (17 coalesced)

  auto xload = [&](int kc) {
    const int base = kc * 64 + sA_kg * 8;
    ca = *(const int4*)&x[xrow + base];
    cb = *(const int4*)&x[xrow + base + 4];
    cc = (base + 8 < 512) ? x[xrow + base + 8] : 0;
  };

  auto wload = [&](int kc) {           // wave-uniform col, lane = o: coalesced
    const int cbase = kc * 64 + 16 * wave - 2 * y - 1;
    #pragma unroll
    for (int j = 0; j < 17; ++j) {
      const int c = cbase + j;
      f[j] = (c >= 0 && c < 496) ? Wm[c * 64 + lane] : 0.0f;
    }
  };

  // bytes -> windows -> fp16(1024+v) via 0x6400|v; P-trick packing
  auto astage = [&](u16* dstb) {
    const u32 c0 = (u32)ca.x, c1 = (u32)ca.y, c2 = (u32)ca.z, c3 = (u32)ca.w;
    const u32 c4 = (u32)cb.x, c5 = (u32)cb.y, c6 = (u32)cb.z, c7 = (u32)cb.w;
    const u32 c8 = (u32)cc;
    const u32 P0 = ((c0 << 8) | c1) | (((c1 << 8) | c2) << 16);
    const u32 P1 = ((c2 << 8) | c3) | (((c3 << 8) | c4) << 16);
    const u32 P2 = ((c4 << 8) | c5) | (((c5 << 8) | c6) << 16);
    const u32 P3 = ((c6 << 8) | c7) | (((c7 << 8) | c8) << 16);
    u16* arow = &dstb[(sA_sub * 8 + sA_qh * 4) * LSTRIDE + sA_kg * 8];
    #pragma unroll
    for (int qi = 0; qi < 4; ++qi) {
      const int sh = 8 - (sA_qh * 4 + qi);
      int4 d;
      d.x = (int)(((P0 >> sh) & 0x00FF00FFu) | 0x64006400u);
      d.y = (int)(((P1 >> sh) & 0x00FF00FFu) | 0x64006400u);
      d.z = (int)(((P2 >> sh) & 0x00FF00FFu) | 0x64006400u);
      d.w = (int)(((P3 >> sh) & 0x00FF00FFu) | 0x64006400u);
      *(int4*)(arow + qi * LSTRIDE) = d;   // rows 16B-aligned (144B pitch)
    }
  };

  // f[0..16] -> fp16 -> two m-groups x two p-shifts, one b128 write each
  auto bstage = [&](u16* dstb) {
    u16 h[17];
    #pragma unroll
    for (int j = 0; j < 17; ++j)
      h[j] = __builtin_bit_cast(unsigned short, (_Float16)f[j]);
    #pragma unroll
    for (int j = 1; j <= 16; ++j) csum_local += f[j];  // pp=0 coverage: full W
    #pragma unroll
    for (int g = 0; g < 2; ++g) {
      const int mgrp = 2 * wave + g;
      #pragma unroll
      for (int pp = 0; pp < 2; ++pp) {
        const int jb = g * 8 + 1 - pp;
        int4 d;
        d.x = (int)((u32)h[jb + 0] | ((u32)h[jb + 1] << 16));
        d.y = (int)((u32)h[jb + 2] | ((u32)h[jb + 3] << 16));
        d.z = (int)((u32)h[jb + 4] | ((u32)h[jb + 5] << 16));
        d.w = (int)((u32)h[jb + 6] | ((u32)h[jb + 7] << 16));
        *(int4*)&dstb[(pp * 64 + lane) * LSTRIDE + mgrp * 8] = d;  // aligned
      }
    }
  };

  auto compute = [&](const u16* Ab, const u16* Bb) {
    #pragma unroll
    for (int ks = 0; ks < 2; ++ks) {
      const int koff = ks * 32 + quad * 8;
      half8 af[4], bf[4];
      #pragma unroll
      for (int mt = 0; mt < 4; ++mt)
        af[mt] = *(const half8*)&Ab[(wm * 64 + mt * 16 + l16) * LSTRIDE + koff];
      #pragma unroll
      for (int nt = 0; nt < 4; ++nt)
        bf[nt] = *(const half8*)&Bb[(wn * 64 + nt * 16 + l16) * LSTRIDE + koff];
      #pragma unroll
      for (int mt = 0; mt < 4; ++mt)
        #pragma unroll
        for (int nt = 0; nt < 4; ++nt)
          acc[mt][nt] = __builtin_amdgcn_mfma_f32_16x16x32_f16(
              af[mt], bf[nt], acc[mt][nt], 0, 0, 0);
    }
  };

  // ---- prologue: fill buffer 0
  xload(0); wload(0);
  astage(arena); bstage(arena + 2 * BIMG);
  __syncthreads();

  // ---- main loop: one barrier per k-chunk (dbuf makes it sufficient)
  #pragma unroll
  for (int kc = 0; kc < 8; ++kc) {
    u16* Acur = arena + (kc & 1) * BIMG;
    u16* Bcur = arena + (2 + (kc & 1)) * BIMG;
    u16* Anxt = arena + ((kc + 1) & 1) * BIMG;
    u16* Bnxt = arena + (2 + ((kc + 1) & 1)) * BIMG;
    if (kc < 7) { xload(kc + 1); wload(kc + 1); }  // latency under MFMA below
    compute(Acur, Bcur);
    if (kc < 7) { astage(Anxt); bstage(Bnxt); }    // VALU in MFMA shadow
    __syncthreads();
  }

  // ---- csum reduction: part[wave*64+o] -> K1*colsum(W)
  const float S = 2.0f / 255.0f;
  const float K1 = 1024.0f * S + 1.0f;
  part[t] = csum_local;
  __syncthreads();
  if (t < 64)
    csumsh[t] = K1 * (part[t] + part[t + 64] + part[t + 128] + part[t + 192]);
  __syncthreads();

  float cs[4];
  #pragma unroll
  for (int nt = 0; nt < 4; ++nt) cs[nt] = csumsh[nt * 16 + l16];

  // ---- epilogue: stage to LDS (16 chunks x 4KB, pitch 1040 floats), then
  // fully-coalesced stores: per wave-instr 64 lanes x 16B = 1KB contiguous.
  float* ep = (float*)arena;           // 66560 B used <= 73728
  #pragma unroll
  for (int mt = 0; mt < 4; ++mt) {
    #pragma unroll
    for (int i = 0; i < 4; ++i) {
      const int mr = wm * 64 + mt * 16 + quad * 4 + i;   // 0..127
      const int sub_l = mr >> 3, q = mr & 7;
      const int rowbase = sub_l * 1040 + wn * 512 + q * 64 + l16;
      #pragma unroll
      for (int nt = 0; nt < 4; ++nt)
        ep[rowbase + nt * 16] = S * acc[mt][nt][i] - cs[nt];
    }
  }
  __syncthreads();

  const long outbase = (long)mtile * 16 * 8192 + (long)y * 1024;
  #pragma unroll
  for (int k2 = 0; k2 < 16; ++k2) {
    const float4 v =
        *(const float4*)((const char*)ep + k2 * 4160 + wave * 1024 + lane * 16);
    *(float4*)&out[outbase + (long)k2 * 8192 + wave * 256 + lane * 4] = v;
  }
}

extern "C" void kernel_launch(void* const* d_in, const int* in_sizes, int n_in,
                              void* d_out, int out_size, void* d_ws, size_t ws_size,
                              hipStream_t stream) {
  const int* x = (const int*)d_in[0];        // (256, 4096) byte values as int32
  const float* Wm = (const float*)d_in[1];   // (496, 64) fp32
  float* out = (float*)d_out;                // (256, 8, 128, 64) fp32
  byteformer_fused<<<dim3(128, 8), dim3(256), 0, stream>>>(x, Wm, out);
}